// Round 15
// baseline (139.885 us; speedup 1.0000x reference)
//
#include <hip/hip_runtime.h>
#include <hip/hip_bf16.h>

#define NPIX (8*128*128)   // 131072 pixels
#define CH   256
#define PPB  128           // pixels per block
#define SCALE 4.774648292756860f   // 30/(2*pi): sin arg in revolutions

typedef __attribute__((ext_vector_type(8))) short bf16x8;
typedef __attribute__((ext_vector_type(4))) float f32x4;

__device__ inline unsigned int pkbf(float a, float b) {
    union { __hip_bfloat162 h; unsigned int u; } c;
    c.h = __float22bfloat162_rn(float2{a, b});
    return c.u;
}
__device__ inline unsigned short f2bf(float f) {
    unsigned int u = __float_as_uint(f);
    return (unsigned short)((u + 0x7FFFu + ((u >> 16) & 1u)) >> 16);  // RNE
}
// sin(2*pi*t) = v_fract + v_sin
__device__ inline float sinrev(float t) {
    return __builtin_amdgcn_sinf(__builtin_amdgcn_fractf(t));
}
// within-32-chunk K permutation: k = chunk + nf16*16 + lm -> chunk + lm*2 + nf16
__device__ inline int kperm32(int k) {
    return (k & ~31) | ((k & 15) << 1) | ((k >> 4) & 1);
}

// Weights -> bf16, pre-scaled by 30/(2pi). W2 [256][256] K-permuted cols;
// W1 [256][12] padded [256][16]; W4 [3][256] padded [16][256] (rows 3..15 zero),
// K-permuted cols.
__global__ __launch_bounds__(256) void conv_weights(
    const float* __restrict__ W1, const float* __restrict__ W2,
    const float* __restrict__ W4,
    unsigned short* __restrict__ W2b, unsigned short* __restrict__ W1b,
    unsigned short* __restrict__ W4b)
{
    if (blockIdx.x < 256) {
        const int o = blockIdx.x, k = threadIdx.x;
        W2b[o*CH + kperm32(k)] = f2bf(W2[o*CH + k] * SCALE);
    } else {
        const int t = threadIdx.x;
        #pragma unroll
        for (int j = 0; j < 16; ++j)
            W1b[t*16 + j] = (j < 12) ? f2bf(W1[t*12 + j] * SCALE) : (unsigned short)0;
        const int kp = kperm32(t);
        #pragma unroll
        for (int r = 0; r < 16; ++r)
            W4b[r*CH + kp] = (r < 3) ? f2bf(W4[r*CH + t] * SCALE) : (unsigned short)0;
    }
}

// Fused SIREN 12->256->256->3, all matmuls MFMA (PRE path).
// Block = 128 pixels x 256 ch, 512 thr = 8 waves in a 2(M) x 4(N) grid:
// wave (wm,wn) owns pixels [wm*64,+64) x out-ch [wn*64,+64), acc[4][4].
// h [128 pix][256 k'] bf16 LDS (64 KB), K'-permuted, XOR-swizzled (pix&31)<<4.
// x [128 pix][32 k] bf16 LDS rows padded to 80 B (10 KB); each of 4 slots/row
// writes a FULL 16 B (slot0 = ch0..7, slot1 = ch8..11 + zeros, slots2,3 = zeros)
// so the 64 B read span of the layer-1 A-fragments is fully initialized.
template<bool PRE>
__global__ __launch_bounds__(512, 4) void rendernet6(
    const float* __restrict__ z,
    const float* __restrict__ nrm,
    const float* __restrict__ sph,
    const float* __restrict__ pc,
    const float* __restrict__ vd,
    const float* __restrict__ W1,
    const float* __restrict__ b1,
    const float* __restrict__ W2f,
    const unsigned short* __restrict__ W2b,
    const unsigned short* __restrict__ W1b,
    const float* __restrict__ b2,
    const float* __restrict__ W4f,
    const unsigned short* __restrict__ W4b,
    const float* __restrict__ b4,
    float* __restrict__ out)
{
    __shared__ __align__(16) char smem[PPB*512 + PPB*80];   // 64 KB h + 10 KB x
    char* xb = smem + PPB*512;

    const int tid     = threadIdx.x;
    const int lane    = tid & 63;
    const int wave    = tid >> 6;        // 0..7
    const int wm      = wave >> 2;       // 0..1 : pixel half
    const int wn      = wave & 3;        // 0..3 : ch quadrant
    const int lm      = lane & 15;       // A row / B,D col
    const int lg      = lane >> 4;       // k-group of 8 / D row-group of 4
    const int m0      = wm * 64;         // pixel base within block
    const int n0      = wn * 64;         // out-ch base
    const int pixbase = blockIdx.x * PPB;

    f32x4 acc[4][4];

    // ================= layer 1 =================
    if constexpr (PRE) {
        // stage x[128 pix][32 k]: thread = (pix = tid&127, slot = tid>>7 in 0..3),
        // each slot writes 16 B -> full 64 B per row initialized.
        {
            const int p  = tid & 127;
            const int sl = tid >> 7;
            const int gp = pixbase + p;
            union { unsigned int w[4]; bf16x8 v; } t;
            t.w[0] = t.w[1] = t.w[2] = t.w[3] = 0u;
            if (sl == 0) {
                t.w[0] = pkbf(sph[0*NPIX+gp], sph[1*NPIX+gp]);
                t.w[1] = pkbf(sph[2*NPIX+gp], nrm[0*NPIX+gp]);
                t.w[2] = pkbf(nrm[1*NPIX+gp], nrm[2*NPIX+gp]);
                t.w[3] = pkbf(pc [0*NPIX+gp], pc [1*NPIX+gp]);
            } else if (sl == 1) {
                t.w[0] = pkbf(pc[2*NPIX+gp], vd[0*NPIX+gp]);
                t.w[1] = pkbf(vd[1*NPIX+gp], vd[2*NPIX+gp]);
            }
            *(bf16x8*)(xb + p*80 + sl*16) = t.v;
        }
        __syncthreads();

        // bias-preloaded accumulators (revolutions)
        #pragma unroll
        for (int nf = 0; nf < 4; ++nf) {
            const float bv = b1[n0 + nf*16 + lm] * SCALE;
            #pragma unroll
            for (int mf = 0; mf < 4; ++mf) acc[mf][nf] = (f32x4){bv, bv, bv, bv};
        }

        bf16x8 w1f[4];
        #pragma unroll
        for (int nf = 0; nf < 4; ++nf) {
            bf16x8 t = *(const bf16x8*)(W1b + (n0 + nf*16 + lm)*16 + (lg & 1)*8);
            w1f[nf] = (lg < 2) ? t : (bf16x8){0,0,0,0,0,0,0,0};
        }
        bf16x8 ax[4];
        #pragma unroll
        for (int mf = 0; mf < 4; ++mf)
            ax[mf] = *(const bf16x8*)(xb + (m0 + mf*16 + lm)*80 + lg*16);

        #pragma unroll
        for (int nf = 0; nf < 4; ++nf)
            #pragma unroll
            for (int mf = 0; mf < 4; ++mf)
                acc[mf][nf] = __builtin_amdgcn_mfma_f32_16x16x32_bf16(
                                  ax[mf], w1f[nf], acc[mf][nf], 0, 0, 0);

        // h1 = sin(2pi*acc): pair (nf0,nf1) -> chunk n0, (nf2,nf3) -> chunk n0+32
        #pragma unroll
        for (int mf = 0; mf < 4; ++mf)
            #pragma unroll
            for (int r = 0; r < 4; ++r) {
                const int pix = m0 + mf*16 + lg*4 + r;
                const int swz = (pix & 31) << 4;
                *(unsigned int*)(smem + pix*512 + ((n0*2 + lm*4) ^ swz)) =
                    pkbf(sinrev(acc[mf][0][r]), sinrev(acc[mf][1][r]));
                *(unsigned int*)(smem + pix*512 + (((n0+32)*2 + lm*4) ^ swz)) =
                    pkbf(sinrev(acc[mf][2][r]), sinrev(acc[mf][3][r]));
            }
    } else {
        // fallback: fp32 VALU layer 1; thread = (pix = tid&127, 64-ch chunk)
        const int p  = tid & 127;
        const int c0 = (tid >> 7) * 64;
        const int gp = pixbase + p;
        float xv[12];
        #pragma unroll
        for (int k = 0; k < 3; ++k) xv[k]     = sph[k*NPIX + gp];
        #pragma unroll
        for (int k = 0; k < 3; ++k) xv[3 + k] = nrm[k*NPIX + gp];
        #pragma unroll
        for (int k = 0; k < 3; ++k) xv[6 + k] = pc [k*NPIX + gp];
        #pragma unroll
        for (int k = 0; k < 3; ++k) xv[9 + k] = vd [k*NPIX + gp];
        for (int c = 0; c < 64; ++c) {
            const int cc = c0 + c;
            float a = b1[cc];
            #pragma unroll
            for (int k = 0; k < 12; ++k) a += W1[cc*12 + k] * xv[k];
            const int kp = kperm32(cc);
            *(unsigned short*)(smem + p*512 + ((kp*2) ^ ((p & 31) << 4))) =
                f2bf(__sinf(30.0f * a));
        }
    }
    __syncthreads();

    // ================= layer 2: K-loop (K'=256), wave tile 64pix x 64ch =================
    #pragma unroll
    for (int nf = 0; nf < 4; ++nf) {
        const float bv = PRE ? b2[n0 + nf*16 + lm] * SCALE : b2[n0 + nf*16 + lm];
        #pragma unroll
        for (int mf = 0; mf < 4; ++mf) acc[mf][nf] = (f32x4){bv, bv, bv, bv};
    }

    if constexpr (PRE) {
        const unsigned short* bp = W2b + (n0 + lm)*CH + lg*8;
        #pragma unroll
        for (int k0i = 0; k0i < 8; ++k0i) {
            bf16x8 bfr[4];
            #pragma unroll
            for (int nf = 0; nf < 4; ++nf)
                bfr[nf] = *(const bf16x8*)(bp + nf*16*CH + k0i*32);
            bf16x8 afr[4];
            #pragma unroll
            for (int mf = 0; mf < 4; ++mf) {
                const int pr = m0 + mf*16 + lm;
                afr[mf] = *(const bf16x8*)(smem + pr*512 +
                              ((k0i*64 + lg*16) ^ ((pr & 31) << 4)));
            }
            #pragma unroll
            for (int nf = 0; nf < 4; ++nf)
                #pragma unroll
                for (int mf = 0; mf < 4; ++mf)
                    acc[mf][nf] = __builtin_amdgcn_mfma_f32_16x16x32_bf16(
                                      afr[mf], bfr[nf], acc[mf][nf], 0, 0, 0);
        }
    } else {
        #pragma unroll
        for (int k0i = 0; k0i < 8; ++k0i) {
            bf16x8 afr[4];
            #pragma unroll
            for (int mf = 0; mf < 4; ++mf) {
                const int pr = m0 + mf*16 + lm;
                afr[mf] = *(const bf16x8*)(smem + pr*512 +
                              ((k0i*64 + lg*16) ^ ((pr & 31) << 4)));
            }
            #pragma unroll
            for (int nf = 0; nf < 4; ++nf) {
                bf16x8 t;
                #pragma unroll
                for (int j = 0; j < 8; ++j) {
                    const int kp = k0i*32 + lg*8 + j;
                    const int kr = (kp & ~31) | ((kp & 1) << 4) | ((kp >> 1) & 15);
                    t[j] = (short)f2bf(W2f[(n0 + nf*16 + lm)*CH + kr]);
                }
                #pragma unroll
                for (int mf = 0; mf < 4; ++mf)
                    acc[mf][nf] = __builtin_amdgcn_mfma_f32_16x16x32_bf16(
                                      afr[mf], t, acc[mf][nf], 0, 0, 0);
            }
        }
    }
    __syncthreads();   // all h1 reads done

    // ================= h2 -> packed pair writes =================
    #pragma unroll
    for (int mf = 0; mf < 4; ++mf)
        #pragma unroll
        for (int r = 0; r < 4; ++r) {
            const int pix = m0 + mf*16 + lg*4 + r;
            const int swz = (pix & 31) << 4;
            unsigned int pk0, pk1;
            if constexpr (PRE) {
                pk0 = pkbf(sinrev(acc[mf][0][r]), sinrev(acc[mf][1][r]));
                pk1 = pkbf(sinrev(acc[mf][2][r]), sinrev(acc[mf][3][r]));
            } else {
                pk0 = pkbf(__sinf(30.0f*acc[mf][0][r]), __sinf(30.0f*acc[mf][1][r]));
                pk1 = pkbf(__sinf(30.0f*acc[mf][2][r]), __sinf(30.0f*acc[mf][3][r]));
            }
            *(unsigned int*)(smem + pix*512 + ((n0*2 + lm*4) ^ swz))      = pk0;
            *(unsigned int*)(smem + pix*512 + (((n0+32)*2 + lm*4) ^ swz)) = pk1;
        }
    __syncthreads();

    // ================= layer 4 (waves 0 and 4): 64-pix half each =================
    if (wn == 0) {
        const float b4v = (lm < 3) ? (PRE ? b4[lm] * SCALE : b4[lm]) : 0.0f;
        f32x4 d[4];
        #pragma unroll
        for (int mf = 0; mf < 4; ++mf) d[mf] = (f32x4){b4v, b4v, b4v, b4v};

        #pragma unroll
        for (int k0i = 0; k0i < 8; ++k0i) {
            bf16x8 b4f;
            if constexpr (PRE) {
                b4f = *(const bf16x8*)(W4b + lm*CH + k0i*32 + lg*8);  // rows 3..15 zero
            } else {
                #pragma unroll
                for (int j = 0; j < 8; ++j) {
                    const int kp = k0i*32 + lg*8 + j;
                    const int kr = (kp & ~31) | ((kp & 1) << 4) | ((kp >> 1) & 15);
                    b4f[j] = (lm < 3) ? (short)f2bf(W4f[lm*CH + kr]) : (short)0;
                }
            }
            bf16x8 afr[4];
            #pragma unroll
            for (int mf = 0; mf < 4; ++mf) {
                const int pr = m0 + mf*16 + lm;
                afr[mf] = *(const bf16x8*)(smem + pr*512 +
                              ((k0i*64 + lg*16) ^ ((pr & 31) << 4)));
            }
            #pragma unroll
            for (int mf = 0; mf < 4; ++mf)
                d[mf] = __builtin_amdgcn_mfma_f32_16x16x32_bf16(
                            afr[mf], b4f, d[mf], 0, 0, 0);
        }

        if (lm < 3) {
            #pragma unroll
            for (int mf = 0; mf < 4; ++mf)
                #pragma unroll
                for (int r = 0; r < 4; ++r) {
                    const int pix = m0 + mf*16 + lg*4 + r;
                    const int gi  = lm*NPIX + pixbase + pix;
                    const float sv = PRE ? sinrev(d[mf][r]) : __sinf(30.0f * d[mf][r]);
                    out[gi] = z[gi] + 0.5f * sv;
                }
        }
    }
}

extern "C" void kernel_launch(void* const* d_in, const int* in_sizes, int n_in,
                              void* d_out, int out_size, void* d_ws, size_t ws_size,
                              hipStream_t stream) {
    const float* z   = (const float*)d_in[0];
    const float* nrm = (const float*)d_in[1];
    // d_in[2] = ad : unused by the reference
    const float* s   = (const float*)d_in[3];
    const float* pc  = (const float*)d_in[4];
    const float* vd  = (const float*)d_in[5];
    const float* W1  = (const float*)d_in[6];
    const float* b1  = (const float*)d_in[7];
    const float* W2  = (const float*)d_in[8];
    const float* b2  = (const float*)d_in[9];
    const float* W4  = (const float*)d_in[10];
    const float* b4  = (const float*)d_in[11];
    float* out = (float*)d_out;

    const size_t need = (size_t)(CH*CH + 16*CH + 16*CH) * sizeof(unsigned short); // 144 KB
    if (ws_size >= need) {
        unsigned short* W2b = (unsigned short*)d_ws;
        unsigned short* W1b = W2b + CH*CH;
        unsigned short* W4b = W1b + 16*CH;
        conv_weights<<<dim3(257), dim3(256), 0, stream>>>(W1, W2, W4, W2b, W1b, W4b);
        rendernet6<true><<<dim3(NPIX/PPB), dim3(512), 0, stream>>>(
            z, nrm, s, pc, vd, W1, b1, W2, W2b, W1b, b2, W4, W4b, b4, out);
    } else {
        rendernet6<false><<<dim3(NPIX/PPB), dim3(512), 0, stream>>>(
            z, nrm, s, pc, vd, W1, b1, W2, nullptr, nullptr, b2, W4, nullptr, b4, out);
    }
}

// Round 16
// 132.822 us; speedup vs baseline: 1.0532x; 1.0532x over previous
//
#include <hip/hip_runtime.h>
#include <hip/hip_bf16.h>

#define NPIX (8*128*128)   // 131072 pixels
#define CH   256
#define PPB  128           // pixels per block
#define SCALE 4.774648292756860f   // 30/(2*pi): sin arg in revolutions

typedef __attribute__((ext_vector_type(8))) short bf16x8;
typedef __attribute__((ext_vector_type(4))) float f32x4;

__device__ inline unsigned int pkbf(float a, float b) {
    union { __hip_bfloat162 h; unsigned int u; } c;
    c.h = __float22bfloat162_rn(float2{a, b});
    return c.u;
}
__device__ inline unsigned short f2bf(float f) {
    unsigned int u = __float_as_uint(f);
    return (unsigned short)((u + 0x7FFFu + ((u >> 16) & 1u)) >> 16);  // RNE
}
// sin(2*pi*t) = v_fract + v_sin
__device__ inline float sinrev(float t) {
    return __builtin_amdgcn_sinf(__builtin_amdgcn_fractf(t));
}
// within-32-chunk K permutation: k = chunk + nf16*16 + lm -> chunk + lm*2 + nf16
__device__ inline int kperm32(int k) {
    return (k & ~31) | ((k & 15) << 1) | ((k >> 4) & 1);
}

// Weights -> bf16, pre-scaled by 30/(2pi). W2 [256][256] K-permuted cols;
// W1 [256][12] padded [256][16]; W4 [3][256] padded [16][256] (rows 3..15 zero),
// K-permuted cols.
__global__ __launch_bounds__(256) void conv_weights(
    const float* __restrict__ W1, const float* __restrict__ W2,
    const float* __restrict__ W4,
    unsigned short* __restrict__ W2b, unsigned short* __restrict__ W1b,
    unsigned short* __restrict__ W4b)
{
    if (blockIdx.x < 256) {
        const int o = blockIdx.x, k = threadIdx.x;
        W2b[o*CH + kperm32(k)] = f2bf(W2[o*CH + k] * SCALE);
    } else {
        const int t = threadIdx.x;
        #pragma unroll
        for (int j = 0; j < 16; ++j)
            W1b[t*16 + j] = (j < 12) ? f2bf(W1[t*12 + j] * SCALE) : (unsigned short)0;
        const int kp = kperm32(t);
        #pragma unroll
        for (int r = 0; r < 16; ++r)
            W4b[r*CH + kp] = (r < 3) ? f2bf(W4[r*CH + t] * SCALE) : (unsigned short)0;
    }
}

// Fused SIREN 12->256->256->3, all matmuls MFMA (PRE path).
// Block = 128 pixels x 256 ch, 512 thr = 8 waves in a 2(M) x 4(N) grid:
// wave (wm,wn) owns pixels [wm*64,+64) x out-ch [wn*64,+64), acc[4][4].
// h [128 pix][256 k'] bf16 LDS (64 KB), K'-permuted, XOR-swizzled (pix&31)<<4.
// x [128 pix][32 k] bf16 LDS rows padded to 80 B (10 KB).
// NOTE (512,2): R15 showed (512,4) makes the allocator pick the 64-reg tier and
// spill acc[4][4] to scratch (WRITE_SIZE 87 MB). 256-reg cap removes the spill;
// actual need ~120 regs -> expect 4 waves/SIMD, 2 blocks/CU (LDS-matched).
template<bool PRE>
__global__ __launch_bounds__(512, 2) void rendernet7(
    const float* __restrict__ z,
    const float* __restrict__ nrm,
    const float* __restrict__ sph,
    const float* __restrict__ pc,
    const float* __restrict__ vd,
    const float* __restrict__ W1,
    const float* __restrict__ b1,
    const float* __restrict__ W2f,
    const unsigned short* __restrict__ W2b,
    const unsigned short* __restrict__ W1b,
    const float* __restrict__ b2,
    const float* __restrict__ W4f,
    const unsigned short* __restrict__ W4b,
    const float* __restrict__ b4,
    float* __restrict__ out)
{
    __shared__ __align__(16) char smem[PPB*512 + PPB*80];   // 64 KB h + 10 KB x
    char* xb = smem + PPB*512;

    const int tid     = threadIdx.x;
    const int lane    = tid & 63;
    const int wave    = tid >> 6;        // 0..7
    const int wm      = wave >> 2;       // 0..1 : pixel half
    const int wn      = wave & 3;        // 0..3 : ch quadrant
    const int lm      = lane & 15;       // A row / B,D col
    const int lg      = lane >> 4;       // k-group of 8 / D row-group of 4
    const int m0      = wm * 64;         // pixel base within block
    const int n0      = wn * 64;         // out-ch base
    const int pixbase = blockIdx.x * PPB;

    f32x4 acc[4][4];

    // ================= layer 1 =================
    if constexpr (PRE) {
        // stage x[128 pix][32 k]: thread = (pix = tid&127, slot = tid>>7 in 0..3),
        // each slot writes 16 B -> full 64 B per row initialized.
        {
            const int p  = tid & 127;
            const int sl = tid >> 7;
            const int gp = pixbase + p;
            union { unsigned int w[4]; bf16x8 v; } t;
            t.w[0] = t.w[1] = t.w[2] = t.w[3] = 0u;
            if (sl == 0) {
                t.w[0] = pkbf(sph[0*NPIX+gp], sph[1*NPIX+gp]);
                t.w[1] = pkbf(sph[2*NPIX+gp], nrm[0*NPIX+gp]);
                t.w[2] = pkbf(nrm[1*NPIX+gp], nrm[2*NPIX+gp]);
                t.w[3] = pkbf(pc [0*NPIX+gp], pc [1*NPIX+gp]);
            } else if (sl == 1) {
                t.w[0] = pkbf(pc[2*NPIX+gp], vd[0*NPIX+gp]);
                t.w[1] = pkbf(vd[1*NPIX+gp], vd[2*NPIX+gp]);
            }
            *(bf16x8*)(xb + p*80 + sl*16) = t.v;
        }
        __syncthreads();

        // bias-preloaded accumulators (revolutions)
        #pragma unroll
        for (int nf = 0; nf < 4; ++nf) {
            const float bv = b1[n0 + nf*16 + lm] * SCALE;
            #pragma unroll
            for (int mf = 0; mf < 4; ++mf) acc[mf][nf] = (f32x4){bv, bv, bv, bv};
        }

        bf16x8 w1f[4];
        #pragma unroll
        for (int nf = 0; nf < 4; ++nf) {
            bf16x8 t = *(const bf16x8*)(W1b + (n0 + nf*16 + lm)*16 + (lg & 1)*8);
            w1f[nf] = (lg < 2) ? t : (bf16x8){0,0,0,0,0,0,0,0};
        }
        bf16x8 ax[4];
        #pragma unroll
        for (int mf = 0; mf < 4; ++mf)
            ax[mf] = *(const bf16x8*)(xb + (m0 + mf*16 + lm)*80 + lg*16);

        #pragma unroll
        for (int nf = 0; nf < 4; ++nf)
            #pragma unroll
            for (int mf = 0; mf < 4; ++mf)
                acc[mf][nf] = __builtin_amdgcn_mfma_f32_16x16x32_bf16(
                                  ax[mf], w1f[nf], acc[mf][nf], 0, 0, 0);

        // h1 = sin(2pi*acc): pair (nf0,nf1) -> chunk n0, (nf2,nf3) -> chunk n0+32
        #pragma unroll
        for (int mf = 0; mf < 4; ++mf)
            #pragma unroll
            for (int r = 0; r < 4; ++r) {
                const int pix = m0 + mf*16 + lg*4 + r;
                const int swz = (pix & 31) << 4;
                *(unsigned int*)(smem + pix*512 + ((n0*2 + lm*4) ^ swz)) =
                    pkbf(sinrev(acc[mf][0][r]), sinrev(acc[mf][1][r]));
                *(unsigned int*)(smem + pix*512 + (((n0+32)*2 + lm*4) ^ swz)) =
                    pkbf(sinrev(acc[mf][2][r]), sinrev(acc[mf][3][r]));
            }
    } else {
        // fallback: fp32 VALU layer 1; thread = (pix = tid&127, 64-ch chunk)
        const int p  = tid & 127;
        const int c0 = (tid >> 7) * 64;
        const int gp = pixbase + p;
        float xv[12];
        #pragma unroll
        for (int k = 0; k < 3; ++k) xv[k]     = sph[k*NPIX + gp];
        #pragma unroll
        for (int k = 0; k < 3; ++k) xv[3 + k] = nrm[k*NPIX + gp];
        #pragma unroll
        for (int k = 0; k < 3; ++k) xv[6 + k] = pc [k*NPIX + gp];
        #pragma unroll
        for (int k = 0; k < 3; ++k) xv[9 + k] = vd [k*NPIX + gp];
        for (int c = 0; c < 64; ++c) {
            const int cc = c0 + c;
            float a = b1[cc];
            #pragma unroll
            for (int k = 0; k < 12; ++k) a += W1[cc*12 + k] * xv[k];
            const int kp = kperm32(cc);
            *(unsigned short*)(smem + p*512 + ((kp*2) ^ ((p & 31) << 4))) =
                f2bf(__sinf(30.0f * a));
        }
    }
    __syncthreads();

    // ================= layer 2: K-loop (K'=256), wave tile 64pix x 64ch =================
    #pragma unroll
    for (int nf = 0; nf < 4; ++nf) {
        const float bv = PRE ? b2[n0 + nf*16 + lm] * SCALE : b2[n0 + nf*16 + lm];
        #pragma unroll
        for (int mf = 0; mf < 4; ++mf) acc[mf][nf] = (f32x4){bv, bv, bv, bv};
    }

    if constexpr (PRE) {
        const unsigned short* bp = W2b + (n0 + lm)*CH + lg*8;
        #pragma unroll
        for (int k0i = 0; k0i < 8; ++k0i) {
            bf16x8 bfr[4];
            #pragma unroll
            for (int nf = 0; nf < 4; ++nf)
                bfr[nf] = *(const bf16x8*)(bp + nf*16*CH + k0i*32);
            bf16x8 afr[4];
            #pragma unroll
            for (int mf = 0; mf < 4; ++mf) {
                const int pr = m0 + mf*16 + lm;
                afr[mf] = *(const bf16x8*)(smem + pr*512 +
                              ((k0i*64 + lg*16) ^ ((pr & 31) << 4)));
            }
            #pragma unroll
            for (int nf = 0; nf < 4; ++nf)
                #pragma unroll
                for (int mf = 0; mf < 4; ++mf)
                    acc[mf][nf] = __builtin_amdgcn_mfma_f32_16x16x32_bf16(
                                      afr[mf], bfr[nf], acc[mf][nf], 0, 0, 0);
        }
    } else {
        #pragma unroll
        for (int k0i = 0; k0i < 8; ++k0i) {
            bf16x8 afr[4];
            #pragma unroll
            for (int mf = 0; mf < 4; ++mf) {
                const int pr = m0 + mf*16 + lm;
                afr[mf] = *(const bf16x8*)(smem + pr*512 +
                              ((k0i*64 + lg*16) ^ ((pr & 31) << 4)));
            }
            #pragma unroll
            for (int nf = 0; nf < 4; ++nf) {
                bf16x8 t;
                #pragma unroll
                for (int j = 0; j < 8; ++j) {
                    const int kp = k0i*32 + lg*8 + j;
                    const int kr = (kp & ~31) | ((kp & 1) << 4) | ((kp >> 1) & 15);
                    t[j] = (short)f2bf(W2f[(n0 + nf*16 + lm)*CH + kr]);
                }
                #pragma unroll
                for (int mf = 0; mf < 4; ++mf)
                    acc[mf][nf] = __builtin_amdgcn_mfma_f32_16x16x32_bf16(
                                      afr[mf], t, acc[mf][nf], 0, 0, 0);
            }
        }
    }
    __syncthreads();   // all h1 reads done

    // ================= h2 -> packed pair writes =================
    #pragma unroll
    for (int mf = 0; mf < 4; ++mf)
        #pragma unroll
        for (int r = 0; r < 4; ++r) {
            const int pix = m0 + mf*16 + lg*4 + r;
            const int swz = (pix & 31) << 4;
            unsigned int pk0, pk1;
            if constexpr (PRE) {
                pk0 = pkbf(sinrev(acc[mf][0][r]), sinrev(acc[mf][1][r]));
                pk1 = pkbf(sinrev(acc[mf][2][r]), sinrev(acc[mf][3][r]));
            } else {
                pk0 = pkbf(__sinf(30.0f*acc[mf][0][r]), __sinf(30.0f*acc[mf][1][r]));
                pk1 = pkbf(__sinf(30.0f*acc[mf][2][r]), __sinf(30.0f*acc[mf][3][r]));
            }
            *(unsigned int*)(smem + pix*512 + ((n0*2 + lm*4) ^ swz))      = pk0;
            *(unsigned int*)(smem + pix*512 + (((n0+32)*2 + lm*4) ^ swz)) = pk1;
        }
    __syncthreads();

    // ================= layer 4 (waves 0 and 4): 64-pix half each =================
    if (wn == 0) {
        const float b4v = (lm < 3) ? (PRE ? b4[lm] * SCALE : b4[lm]) : 0.0f;
        f32x4 d[4];
        #pragma unroll
        for (int mf = 0; mf < 4; ++mf) d[mf] = (f32x4){b4v, b4v, b4v, b4v};

        #pragma unroll
        for (int k0i = 0; k0i < 8; ++k0i) {
            bf16x8 b4f;
            if constexpr (PRE) {
                b4f = *(const bf16x8*)(W4b + lm*CH + k0i*32 + lg*8);  // rows 3..15 zero
            } else {
                #pragma unroll
                for (int j = 0; j < 8; ++j) {
                    const int kp = k0i*32 + lg*8 + j;
                    const int kr = (kp & ~31) | ((kp & 1) << 4) | ((kp >> 1) & 15);
                    b4f[j] = (lm < 3) ? (short)f2bf(W4f[lm*CH + kr]) : (short)0;
                }
            }
            bf16x8 afr[4];
            #pragma unroll
            for (int mf = 0; mf < 4; ++mf) {
                const int pr = m0 + mf*16 + lm;
                afr[mf] = *(const bf16x8*)(smem + pr*512 +
                              ((k0i*64 + lg*16) ^ ((pr & 31) << 4)));
            }
            #pragma unroll
            for (int mf = 0; mf < 4; ++mf)
                d[mf] = __builtin_amdgcn_mfma_f32_16x16x32_bf16(
                            afr[mf], b4f, d[mf], 0, 0, 0);
        }

        if (lm < 3) {
            #pragma unroll
            for (int mf = 0; mf < 4; ++mf)
                #pragma unroll
                for (int r = 0; r < 4; ++r) {
                    const int pix = m0 + mf*16 + lg*4 + r;
                    const int gi  = lm*NPIX + pixbase + pix;
                    const float sv = PRE ? sinrev(d[mf][r]) : __sinf(30.0f * d[mf][r]);
                    out[gi] = z[gi] + 0.5f * sv;
                }
        }
    }
}

extern "C" void kernel_launch(void* const* d_in, const int* in_sizes, int n_in,
                              void* d_out, int out_size, void* d_ws, size_t ws_size,
                              hipStream_t stream) {
    const float* z   = (const float*)d_in[0];
    const float* nrm = (const float*)d_in[1];
    // d_in[2] = ad : unused by the reference
    const float* s   = (const float*)d_in[3];
    const float* pc  = (const float*)d_in[4];
    const float* vd  = (const float*)d_in[5];
    const float* W1  = (const float*)d_in[6];
    const float* b1  = (const float*)d_in[7];
    const float* W2  = (const float*)d_in[8];
    const float* b2  = (const float*)d_in[9];
    const float* W4  = (const float*)d_in[10];
    const float* b4  = (const float*)d_in[11];
    float* out = (float*)d_out;

    const size_t need = (size_t)(CH*CH + 16*CH + 16*CH) * sizeof(unsigned short); // 144 KB
    if (ws_size >= need) {
        unsigned short* W2b = (unsigned short*)d_ws;
        unsigned short* W1b = W2b + CH*CH;
        unsigned short* W4b = W1b + 16*CH;
        conv_weights<<<dim3(257), dim3(256), 0, stream>>>(W1, W2, W4, W2b, W1b, W4b);
        rendernet7<true><<<dim3(NPIX/PPB), dim3(512), 0, stream>>>(
            z, nrm, s, pc, vd, W1, b1, W2, W2b, W1b, b2, W4, W4b, b4, out);
    } else {
        rendernet7<false><<<dim3(NPIX/PPB), dim3(512), 0, stream>>>(
            z, nrm, s, pc, vd, W1, b1, W2, nullptr, nullptr, b2, W4, nullptr, b4, out);
    }
}